// Round 2
// baseline (394.489 us; speedup 1.0000x reference)
//
#include <hip/hip_runtime.h>

// OnlineEmbedding: out[b,h,:] = table[ids[b,h], :]
// ids: [819200] int32, table: [1e6 x 64] fp32, out: [819200 x 64] fp32.
// Work item = one 16B chunk of a 256B row. 16 consecutive threads cover one
// row (coalesced 256B read, coalesced write). Each thread handles UNROLL=4
// chunks spaced grid-wide apart so 4 independent gather chains are in flight
// per thread (latency hiding); compiler batches the 4 ids loads then the 4
// table loads. Output uses non-temporal stores to keep L2/L3 for table rows.

typedef float f4 __attribute__((ext_vector_type(4)));

__global__ __launch_bounds__(256) void OnlineEmbedding_gather4(
    const int* __restrict__ ids,
    const f4* __restrict__ table,
    f4* __restrict__ out,
    int n_chunks)   // n_ids * 16
{
    const int T = gridDim.x * blockDim.x;
    const int t = blockIdx.x * blockDim.x + threadIdx.x;

    const int i0 = t;
    const int i1 = t + T;
    const int i2 = t + 2 * T;
    const int i3 = t + 3 * T;

    // Grid is sized so 4*T == n_chunks exactly; guards kept for safety.
    int id0 = (i0 < n_chunks) ? ids[i0 >> 4] : 0;
    int id1 = (i1 < n_chunks) ? ids[i1 >> 4] : 0;
    int id2 = (i2 < n_chunks) ? ids[i2 >> 4] : 0;
    int id3 = (i3 < n_chunks) ? ids[i3 >> 4] : 0;

    f4 v0, v1, v2, v3;
    if (i0 < n_chunks) v0 = table[((size_t)id0 << 4) | (i0 & 15)];
    if (i1 < n_chunks) v1 = table[((size_t)id1 << 4) | (i1 & 15)];
    if (i2 < n_chunks) v2 = table[((size_t)id2 << 4) | (i2 & 15)];
    if (i3 < n_chunks) v3 = table[((size_t)id3 << 4) | (i3 & 15)];

    if (i0 < n_chunks) __builtin_nontemporal_store(v0, &out[i0]);
    if (i1 < n_chunks) __builtin_nontemporal_store(v1, &out[i1]);
    if (i2 < n_chunks) __builtin_nontemporal_store(v2, &out[i2]);
    if (i3 < n_chunks) __builtin_nontemporal_store(v3, &out[i3]);
}

extern "C" void kernel_launch(void* const* d_in, const int* in_sizes, int n_in,
                              void* d_out, int out_size, void* d_ws, size_t ws_size,
                              hipStream_t stream) {
    const int* ids   = (const int*)d_in[0];
    const f4*  table = (const f4*)d_in[1];
    f4*        out   = (f4*)d_out;

    const int n_ids    = in_sizes[0];      // 819200
    const int n_chunks = n_ids * 16;       // 13,107,200 float4 chunks
    const int UNROLL   = 4;
    const int block    = 256;
    const int threads  = (n_chunks + UNROLL - 1) / UNROLL;   // 3,276,800
    const int grid     = (threads + block - 1) / block;      // 12,800 blocks

    OnlineEmbedding_gather4<<<grid, block, 0, stream>>>(ids, table, out, n_chunks);
}